// Round 8
// baseline (715.622 us; speedup 1.0000x reference)
//
#include <hip/hip_runtime.h>
#include <math.h>
#include <stdint.h>

#define F_K 802816          // 64*112*112
#define NCH 112             // k-chunks
#define CHF 7168            // floats per chunk (28 tiles x 256)
#define NTL 28              // tiles per chunk
#define PRED_OFF 12845056
#define NORM_OFF 12845568   // PRED_OFF + 512

// ---------------- Kernel 1: row-streaming GEMM  part[c][b][n] -------------------
// grid 896 = 14 chunk-groups x 8 row-groups x 8 xcd-classes.
// bid = cg*64 + rg*8 + cl, chunk c = cg*8+cl  -> the 8 rg-siblings of a chunk
// share bid%8 (same XCD): x tile reads dedupe in that XCD's L2 (~3.6MB hot).
// Block: W rows [16rg,16rg+16), k in [c*7168,(c+1)*7168). Wave w owns rows
// 16rg+4w..+3, streaming them CONTIGUOUSLY in 1KB register loads (ping-pong,
// static wA/wB). x read per-thread straight from global (L1/L2 shared across
// waves & sibling blocks). No LDS, no barriers, no DMA. Epilogue: 6-step
// shuffle butterfly over the 64 k-lanes, lane0 stores 64 results.
__global__ __launch_bounds__(256, 4) void k_gemm1(const float* __restrict__ x,
                                                  const float* __restrict__ w1,
                                                  float* __restrict__ part) {
  const int t = threadIdx.x;
  const int wv = t >> 6, lane = t & 63;
  const int bid = blockIdx.x;
  const int cl = bid & 7, rg = (bid >> 3) & 7, cg = bid >> 6;   // cg in [0,14)
  const int c = cg * 8 + cl;
  const size_t base = (size_t)c * CHF + 4 * lane;

  const float* wrow[4];
#pragma unroll
  for (int i = 0; i < 4; ++i)
    wrow[i] = w1 + (size_t)(16 * rg + 4 * wv + i) * F_K + base;
  const float* xrow = x + base;            // + b*F_K + kt*256

  float acc[16][4];
#pragma unroll
  for (int b = 0; b < 16; ++b)
#pragma unroll
    for (int i = 0; i < 4; ++i) acc[b][i] = 0.f;

#define LOADW(REG, KT_)                                                     \
  { _Pragma("unroll") for (int i_ = 0; i_ < 4; ++i_)                        \
      REG[i_] = *reinterpret_cast<const float4*>(wrow[i_] + (KT_) * 256); }
#define COMPUTE(REG, KT_)                                                   \
  { _Pragma("unroll") for (int b_ = 0; b_ < 16; ++b_) {                     \
      float4 xv = *reinterpret_cast<const float4*>(                         \
          xrow + (size_t)b_ * F_K + (KT_) * 256);                           \
      _Pragma("unroll") for (int i_ = 0; i_ < 4; ++i_) {                    \
        acc[b_][i_] += xv.x * REG[i_].x; acc[b_][i_] += xv.y * REG[i_].y;   \
        acc[b_][i_] += xv.z * REG[i_].z; acc[b_][i_] += xv.w * REG[i_].w;   \
      } } }

  float4 wA[4], wB[4];
  LOADW(wA, 0);
  for (int kt = 0; kt < NTL; kt += 2) {
    LOADW(wB, kt + 1);                 // prefetch odd tile (registers)
    COMPUTE(wA, kt);
    if (kt + 2 < NTL) LOADW(wA, kt + 2);
    COMPUTE(wB, kt + 1);
  }
#undef LOADW
#undef COMPUTE

  // butterfly-reduce each acc slot over the 64 k-lanes
#pragma unroll
  for (int b = 0; b < 16; ++b)
#pragma unroll
    for (int i = 0; i < 4; ++i) {
      float v = acc[b][i];
      v += __shfl_xor(v, 1);  v += __shfl_xor(v, 2);  v += __shfl_xor(v, 4);
      v += __shfl_xor(v, 8);  v += __shfl_xor(v, 16); v += __shfl_xor(v, 32);
      acc[b][i] = v;
    }
  if (lane == 0) {
    float* pp = part + (size_t)c * 2048 + 16 * rg + 4 * wv;
#pragma unroll
    for (int b = 0; b < 16; ++b)
#pragma unroll
      for (int i = 0; i < 4; ++i)
        pp[b * 128 + i] = acc[b][i];
  }
}

// ---------------- Kernel 2a: reduce 112 chunk-partials -> p2[16][128] ----------
__global__ __launch_bounds__(256) void k_red(const float* __restrict__ part,
                                             float* __restrict__ p2) {
  int idx = blockIdx.x * 256 + threadIdx.x;   // 0..2047
  const float* p = part + idx;
  float s = 0.f;
#pragma unroll 8
  for (int q = 0; q < NCH; ++q) s += p[(size_t)q * 2048];
  p2[idx] = s;
}

// ---------------- Kernel 2b: small heads + TPS solve (1 wave / batch) ----------
__global__ __launch_bounds__(64) void k_small(const float* __restrict__ p2,
    const float* __restrict__ b1, const float* __restrict__ W2, const float* __restrict__ b2,
    const float* __restrict__ W3, const float* __restrict__ b3,
    const float* __restrict__ lmean, const float* __restrict__ scales,
    float* __restrict__ dout_pred, float* __restrict__ coef, float* __restrict__ norms) {
  const int b = blockIdx.x, lane = threadIdx.x;
  __shared__ float o[128], dflat[32], fl[32], A[19][22], farr[19], sol[19][2];

  o[lane]      = p2[b * 128 + lane]      + b1[lane];
  o[lane + 64] = p2[b * 128 + 64 + lane] + b1[64 + lane];
  __syncthreads();

  const int j = lane & 31;
  const float* Wm = (lane < 32) ? (W2 + j * 128) : (W3 + j * 128);
  float acc = 0.f;
#pragma unroll 4
  for (int n = 0; n < 128; ++n) acc += o[n] * Wm[n];
  float other = __shfl(acc, j + 32);
  float sc = scales[b];
  float dspv = 0.f;
  if (lane < 32) {
    float predv = acc + b2[j] + lmean[j];
    dspv = (other + b3[j]) * sc;
    dout_pred[b * 32 + j] = predv;
    dflat[j] = predv + dspv;   // dst (flat y,x pairs)
    fl[j] = dspv;              // flows = dst - src
  }
  float s2 = (lane < 32) ? dspv * dspv : 0.f;
  for (int off = 32; off; off >>= 1) s2 += __shfl_xor(s2, off);
  if (lane == 0) norms[b] = sqrtf(s2);
  __syncthreads();

  // build augmented TPS system A[19][19+2]
  for (int cell = lane; cell < 19 * 21; cell += 64) {
    int r = cell / 21, cc = cell - (cell / 21) * 21;
    float v;
    if (r < 16) {
      if (cc < 16) {
        float dy = dflat[2*r] - dflat[2*cc], dx = dflat[2*r+1] - dflat[2*cc+1];
        float d2 = dy * dy + dx * dx;
        v = 0.5f * d2 * logf(fmaxf(d2, 1e-10f));
        if (r == cc) v += 1e-6f;
      } else if (cc == 16) v = dflat[2*r];
      else if (cc == 17) v = dflat[2*r+1];
      else if (cc == 18) v = 1.0f;
      else if (cc == 19) v = fl[2*r];
      else               v = fl[2*r+1];
    } else {
      int rr = r - 16;
      if (cc < 16) v = (rr == 0) ? dflat[2*cc] : (rr == 1) ? dflat[2*cc+1] : 1.0f;
      else         v = 0.0f;
    }
    A[r][cc] = v;
  }
  __syncthreads();

  // Gaussian elimination with partial pivoting
  for (int k = 0; k < 19; ++k) {
    float av = (lane >= k && lane < 19) ? fabsf(A[lane][k]) : -1.0f;
    int idx = lane;
    for (int off = 32; off; off >>= 1) {
      float v2 = __shfl_xor(av, off);
      int  i2 = __shfl_xor(idx, off);
      if (v2 > av) { av = v2; idx = i2; }
    }
    idx = __shfl(idx, 0);
    if (idx != k && lane < 21) {
      float tmp = A[k][lane]; A[k][lane] = A[idx][lane]; A[idx][lane] = tmp;
    }
    __syncthreads();
    float invp = 1.0f / A[k][k];
    if (lane < 19) farr[lane] = (lane > k) ? A[lane][k] * invp : 0.0f;
    __syncthreads();
    int nr = 18 - k, nc = 20 - k;
    for (int cell = lane; cell < nr * nc; cell += 64) {
      int i = k + 1 + cell / nc, jj = k + 1 + cell % nc;
      A[i][jj] -= farr[i] * A[k][jj];
    }
    __syncthreads();
  }
  for (int k = 18; k >= 0; --k) {
    if (lane < 2) sol[k][lane] = A[k][19 + lane] / A[k][k];
    __syncthreads();
    if (lane < 2 * k) {
      int i = lane >> 1, cc = lane & 1;
      A[i][19 + cc] -= A[i][k] * sol[k][cc];
    }
    __syncthreads();
  }
  float* cf = coef + b * 80;
  if (lane < 32) { cf[lane] = sol[lane >> 1][lane & 1]; cf[38 + lane] = dflat[lane]; }
  else if (lane < 38) cf[lane] = sol[16 + ((lane - 32) >> 1)][(lane - 32) & 1];
}

// ---------------- Kernel 3: dense TPS flow + bilinear warp + NHWC->NCHW --------
__global__ __launch_bounds__(256) void k_warp(const float* __restrict__ img,
                                              const float* __restrict__ coef,
                                              const float* __restrict__ norms,
                                              float* __restrict__ out) {
  const int bid = blockIdx.x;
  const int b = bid / 112, y = bid - (bid / 112) * 112;
  const int t = threadIdx.x;
  __shared__ float qy[112], qx[112];
  __shared__ float cw[32], cv[6], cd[32];
  __shared__ float tile[64][113];

  if (bid == 0 && t == 0) {
    float s = 0.f;
    for (int i = 0; i < 16; ++i) s += norms[i];
    out[NORM_OFF] = s * (1.0f / 16.0f);
  }
  const float* cf = coef + b * 80;
  if (t < 70) {
    float v = cf[t];
    if (t < 32) cw[t] = v;
    else if (t < 38) cv[t - 32] = v;
    else cd[t - 38] = v;
  }
  __syncthreads();

  if (t < 112) {
    float fy = (float)y, fx = (float)t;
    float s0 = cv[0] * fy + cv[2] * fx + cv[4];
    float s1 = cv[1] * fy + cv[3] * fx + cv[5];
#pragma unroll
    for (int i = 0; i < 16; ++i) {
      float dy = fy - cd[2 * i], dx = fx - cd[2 * i + 1];
      float d2 = dy * dy + dx * dx;
      float ph = 0.5f * d2 * logf(fmaxf(d2, 1e-10f));
      s0 += ph * cw[2 * i];
      s1 += ph * cw[2 * i + 1];
    }
    qy[t] = fy - s0;
    qx[t] = fx - s1;
  }
  __syncthreads();

  const int wave = t >> 6, lane = t & 63;
#pragma unroll 4
  for (int p = 0; p < 28; ++p) {
    int xx = wave * 28 + p;
    float fy = qy[xx], fx = qx[xx];
    float y0f = fminf(fmaxf(floorf(fy), 0.f), 110.f);
    float x0f = fminf(fmaxf(floorf(fx), 0.f), 110.f);
    float ay = fminf(fmaxf(fy - y0f, 0.f), 1.f);
    float ax = fminf(fmaxf(fx - x0f, 0.f), 1.f);
    int y0 = (int)y0f, x0 = (int)x0f;
    const float* p00 = img + (((size_t)(b * 112 + y0) * 112 + x0) * 64) + lane;
    float v00 = p00[0], v01 = p00[64];
    float v10 = p00[112 * 64], v11 = p00[112 * 64 + 64];
    float top = v00 * (1.f - ax) + v01 * ax;
    float bot = v10 * (1.f - ax) + v11 * ax;
    tile[lane][xx] = top * (1.f - ay) + bot * ay;
  }
  __syncthreads();

  float* ob = out + (size_t)b * 64 * 12544 + y * 112;
  for (int i = 0; i < 28; ++i) {
    int idx = i * 256 + t;
    int cc = idx / 112, xx = idx - cc * 112;
    ob[(size_t)cc * 12544 + xx] = tile[cc][xx];
  }
}

extern "C" void kernel_launch(void* const* d_in, const int* in_sizes, int n_in,
                              void* d_out, int out_size, void* d_ws, size_t ws_size,
                              hipStream_t stream) {
  const float* x      = (const float*)d_in[0];
  const float* img    = (const float*)d_in[1];
  const float* scales = (const float*)d_in[2];
  const float* W1     = (const float*)d_in[3];
  const float* b1     = (const float*)d_in[4];
  const float* W2     = (const float*)d_in[5];
  const float* b2     = (const float*)d_in[6];
  const float* W3     = (const float*)d_in[7];
  const float* b3     = (const float*)d_in[8];
  const float* lmean  = (const float*)d_in[9];
  float* out = (float*)d_out;
  float* ws  = (float*)d_ws;

  float* P1   = ws;                       // 112*2048 floats
  float* P2   = P1 + (size_t)NCH * 2048;  // 2048
  float* COEF = P2 + 2048;                // 16*80
  float* NORM = COEF + 16 * 80;           // 16

  k_gemm1<<<896, 256, 0, stream>>>(x, W1, P1);
  k_red  <<<8, 256, 0, stream>>>(P1, P2);
  k_small<<<16, 64, 0, stream>>>(P2, b1, W2, b2, W3, b3, lmean, scales,
                                 out + PRED_OFF, COEF, NORM);
  k_warp <<<16 * 112, 256, 0, stream>>>(img, COEF, NORM, out);
}

// Round 9
// 195.322 us; speedup vs baseline: 3.6638x; 3.6638x over previous
//
#include <hip/hip_runtime.h>
#include <math.h>
#include <stdint.h>

#define F_K 802816          // 64*112*112
#define NB1 784             // blocks (k-windows)
#define SWS 200704          // subwindow spacing in floats (= F_K/4, 784*256)
#define PRED_OFF 12845056
#define NORM_OFF 12845568   // PRED_OFF + 512

#define AS3 __attribute__((address_space(3)))
#define AS1 __attribute__((address_space(1)))

// async global->LDS, 16B per lane; LDS dest = base + lane*16 (HW), src per-lane.
__device__ __forceinline__ void gload16(const float* gsrc, float* ldsbase) {
  __builtin_amdgcn_global_load_lds((const AS1 uint32_t*)gsrc, (AS3 uint32_t*)ldsbase, 16, 0, 0);
}

// ---------------- Kernel 1: class-spread split-K GEMM  part[blk] = x @ W1^T -----
// IDENTICAL to the R4 structure (36KB LDS, 4 blk/CU, barrier-free, wave-private
// staging, cell-rotation swizzle) except the k->(wave,step) mapping:
// W1/x row stride is 49*64KiB -> all rows congruent mod 64KiB; a contiguous
// 1024-float block chunk spans ONE ~4KB interleave class (channel/L2-slice
// camping). Fix: block's 1024 floats/row = 4 subwindows of 256 spaced
// SWS floats (16KiB apart mod 64KiB). Step kt: wave w works subwindow
// s=(w+kt)&3 at offset (kt>>2)*64 + w*16 -> the 4 waves occupy 4 distinct
// address classes at every instant. Exact k-partition preserved.
__global__ __launch_bounds__(256) void k_gemm1(const float* __restrict__ x,
                                               const float* __restrict__ w1,
                                               float* __restrict__ part) {
  __shared__ __align__(16) float xs[256 * 4];      // 4 KB  (wave w: cells [64w,64w+64))
  __shared__ __align__(16) float ws[2048 * 4];     // 32 KB (wave w: cells [512w,512w+512))
  const int t = threadIdx.x;
  const int wave = t >> 6, lane = t & 63;
  const int nl = t & 15;
  const int bg = (t >> 4) & 3;
  const int c = blockIdx.x;

  // ---- staging base addresses (per-lane, inverse-rotated column), no k-offset
  const float* wsrcb[8];
#pragma unroll
  for (int cc = 0; cc < 8; ++cc) {
    int f = cc * 64 + lane;             // 0..511
    int n = f >> 2, tau = f & 3;
    int qr = (tau - (n >> 1)) & 3;      // cell rotation (2-way banks on read)
    wsrcb[cc] = w1 + (size_t)n * F_K + 4 * qr;
  }
  const float* xsrcb;
  {
    int b = lane >> 2, tau = lane & 3;
    int q = (tau - (b >> 1)) & 3;
    xsrcb = x + (size_t)b * F_K + 4 * q;
  }
  float* xbase = xs + wave * 256;       // 64 cells * 4 floats
  float* wbase = ws + wave * 2048;      // 512 cells * 4 floats

  float acc[4][8];
#pragma unroll
  for (int i = 0; i < 4; ++i)
#pragma unroll
    for (int j = 0; j < 8; ++j) acc[i][j] = 0.f;

  for (int kt = 0; kt < 16; ++kt) {
    // wave's 16-float k-window for this step: subwindow (wave+kt)&3,
    // offset (kt>>2)*64 + wave*16 within it, block column c*256.
    const size_t ko = (size_t)((wave + kt) & 3) * SWS + (size_t)c * 256
                    + ((kt >> 2) << 6) + (wave << 4);
    // no pending ds ops when DMA writes land (wave-local ordering)
    asm volatile("s_waitcnt lgkmcnt(0)" ::: "memory");
    gload16(xsrcb + ko, xbase);
#pragma unroll
    for (int cc = 0; cc < 8; ++cc) gload16(wsrcb[cc] + ko, wbase + cc * 256);
    asm volatile("s_waitcnt vmcnt(0)" ::: "memory");
    __builtin_amdgcn_sched_barrier(0);
#pragma unroll
    for (int q = 0; q < 4; ++q) {
      float4 xv[4];
#pragma unroll
      for (int i = 0; i < 4; ++i) {
        int b = 4 * bg + i;
        int tx = (q + (b >> 1)) & 3;
        xv[i] = *reinterpret_cast<const float4*>(&xbase[b * 16 + 4 * tx]);
      }
      const int tw = (q + (nl >> 1)) & 3;   // 8j contributes 0 mod 4
#pragma unroll
      for (int j = 0; j < 8; ++j) {
        float4 wv = *reinterpret_cast<const float4*>(&wbase[(16 * j + nl) * 16 + 4 * tw]);
#pragma unroll
        for (int i = 0; i < 4; ++i) {
          acc[i][j] += xv[i].x * wv.x;
          acc[i][j] += xv[i].y * wv.y;
          acc[i][j] += xv[i].z * wv.z;
          acc[i][j] += xv[i].w * wv.w;
        }
      }
    }
  }

  // cross-wave K reduction (reuse ws as red[4][2048])
  __syncthreads();
  float* red = ws;
#pragma unroll
  for (int i = 0; i < 4; ++i)
#pragma unroll
    for (int j = 0; j < 8; ++j)
      red[wave * 2048 + (4 * bg + i) * 128 + 16 * j + nl] = acc[i][j];
  __syncthreads();
  const int o8 = t * 8;
  float4 s0 = {0, 0, 0, 0}, s1 = {0, 0, 0, 0};
#pragma unroll
  for (int w = 0; w < 4; ++w) {
    float4 a = *reinterpret_cast<const float4*>(&red[w * 2048 + o8]);
    float4 b = *reinterpret_cast<const float4*>(&red[w * 2048 + o8 + 4]);
    s0.x += a.x; s0.y += a.y; s0.z += a.z; s0.w += a.w;
    s1.x += b.x; s1.y += b.y; s1.z += b.z; s1.w += b.w;
  }
  float* pp = part + (size_t)c * 2048 + o8;
  *reinterpret_cast<float4*>(pp) = s0;
  *reinterpret_cast<float4*>(pp + 4) = s1;
}

// ---------------- Kernel 2a: reduce 784 partials -> 16 partials ----------------
__global__ __launch_bounds__(256) void k_red(const float* __restrict__ part,
                                             float* __restrict__ p2) {
  int pc = blockIdx.x >> 3, ib = blockIdx.x & 7;
  int idx = ib * 256 + threadIdx.x;               // 0..2047
  const float* p = part + (size_t)pc * 49 * 2048 + idx;
  float s = 0.f;
  for (int q = 0; q < 49; ++q) s += p[(size_t)q * 2048];
  p2[pc * 2048 + idx] = s;
}

// ---------------- Kernel 2b: small heads + TPS solve (1 wave / batch) ----------
__global__ __launch_bounds__(64) void k_small(const float* __restrict__ p2,
    const float* __restrict__ b1, const float* __restrict__ W2, const float* __restrict__ b2,
    const float* __restrict__ W3, const float* __restrict__ b3,
    const float* __restrict__ lmean, const float* __restrict__ scales,
    float* __restrict__ dout_pred, float* __restrict__ coef, float* __restrict__ norms) {
  const int b = blockIdx.x, lane = threadIdx.x;
  __shared__ float o[128], dflat[32], fl[32], A[19][22], farr[19], sol[19][2];

  // final K-reduction + b1
  for (int h = 0; h < 2; ++h) {
    int n = lane + 64 * h;
    float s = b1[n];
    for (int pc = 0; pc < 16; ++pc) s += p2[pc * 2048 + b * 128 + n];
    o[n] = s;
  }
  __syncthreads();

  const int j = lane & 31;
  const float* Wm = (lane < 32) ? (W2 + j * 128) : (W3 + j * 128);
  float acc = 0.f;
#pragma unroll 4
  for (int n = 0; n < 128; ++n) acc += o[n] * Wm[n];
  float other = __shfl(acc, j + 32);
  float sc = scales[b];
  float dspv = 0.f;
  if (lane < 32) {
    float predv = acc + b2[j] + lmean[j];
    dspv = (other + b3[j]) * sc;
    dout_pred[b * 32 + j] = predv;
    dflat[j] = predv + dspv;   // dst (flat y,x pairs)
    fl[j] = dspv;              // flows = dst - src
  }
  float s2 = (lane < 32) ? dspv * dspv : 0.f;
  for (int off = 32; off; off >>= 1) s2 += __shfl_xor(s2, off);
  if (lane == 0) norms[b] = sqrtf(s2);
  __syncthreads();

  // build augmented TPS system A[19][19+2]
  for (int cell = lane; cell < 19 * 21; cell += 64) {
    int r = cell / 21, cc = cell - (cell / 21) * 21;
    float v;
    if (r < 16) {
      if (cc < 16) {
        float dy = dflat[2*r] - dflat[2*cc], dx = dflat[2*r+1] - dflat[2*cc+1];
        float d2 = dy * dy + dx * dx;
        v = 0.5f * d2 * logf(fmaxf(d2, 1e-10f));
        if (r == cc) v += 1e-6f;
      } else if (cc == 16) v = dflat[2*r];
      else if (cc == 17) v = dflat[2*r+1];
      else if (cc == 18) v = 1.0f;
      else if (cc == 19) v = fl[2*r];
      else               v = fl[2*r+1];
    } else {
      int rr = r - 16;
      if (cc < 16) v = (rr == 0) ? dflat[2*cc] : (rr == 1) ? dflat[2*cc+1] : 1.0f;
      else         v = 0.0f;
    }
    A[r][cc] = v;
  }
  __syncthreads();

  // Gaussian elimination with partial pivoting
  for (int k = 0; k < 19; ++k) {
    float av = (lane >= k && lane < 19) ? fabsf(A[lane][k]) : -1.0f;
    int idx = lane;
    for (int off = 32; off; off >>= 1) {
      float v2 = __shfl_xor(av, off);
      int  i2 = __shfl_xor(idx, off);
      if (v2 > av) { av = v2; idx = i2; }
    }
    idx = __shfl(idx, 0);
    if (idx != k && lane < 21) {
      float tmp = A[k][lane]; A[k][lane] = A[idx][lane]; A[idx][lane] = tmp;
    }
    __syncthreads();
    float invp = 1.0f / A[k][k];
    if (lane < 19) farr[lane] = (lane > k) ? A[lane][k] * invp : 0.0f;
    __syncthreads();
    int nr = 18 - k, nc = 20 - k;
    for (int cell = lane; cell < nr * nc; cell += 64) {
      int i = k + 1 + cell / nc, jj = k + 1 + cell % nc;
      A[i][jj] -= farr[i] * A[k][jj];
    }
    __syncthreads();
  }
  for (int k = 18; k >= 0; --k) {
    if (lane < 2) sol[k][lane] = A[k][19 + lane] / A[k][k];
    __syncthreads();
    if (lane < 2 * k) {
      int i = lane >> 1, cc = lane & 1;
      A[i][19 + cc] -= A[i][k] * sol[k][cc];
    }
    __syncthreads();
  }
  float* cf = coef + b * 80;
  if (lane < 32) { cf[lane] = sol[lane >> 1][lane & 1]; cf[38 + lane] = dflat[lane]; }
  else if (lane < 38) cf[lane] = sol[16 + ((lane - 32) >> 1)][(lane - 32) & 1];
}

// ---------------- Kernel 3: dense TPS flow + bilinear warp + NHWC->NCHW --------
__global__ __launch_bounds__(256) void k_warp(const float* __restrict__ img,
                                              const float* __restrict__ coef,
                                              const float* __restrict__ norms,
                                              float* __restrict__ out) {
  const int bid = blockIdx.x;
  const int b = bid / 112, y = bid - (bid / 112) * 112;
  const int t = threadIdx.x;
  __shared__ float qy[112], qx[112];
  __shared__ float cw[32], cv[6], cd[32];
  __shared__ float tile[64][113];   // pad 113 -> conflict-free transposed access

  if (bid == 0 && t == 0) {         // finalize landmarks_norm
    float s = 0.f;
    for (int i = 0; i < 16; ++i) s += norms[i];
    out[NORM_OFF] = s * (1.0f / 16.0f);
  }
  const float* cf = coef + b * 80;
  if (t < 70) {
    float v = cf[t];
    if (t < 32) cw[t] = v;
    else if (t < 38) cv[t - 32] = v;
    else cd[t - 38] = v;
  }
  __syncthreads();

  if (t < 112) {
    float fy = (float)y, fx = (float)t;
    float s0 = cv[0] * fy + cv[2] * fx + cv[4];
    float s1 = cv[1] * fy + cv[3] * fx + cv[5];
#pragma unroll
    for (int i = 0; i < 16; ++i) {
      float dy = fy - cd[2 * i], dx = fx - cd[2 * i + 1];
      float d2 = dy * dy + dx * dx;
      float ph = 0.5f * d2 * logf(fmaxf(d2, 1e-10f));
      s0 += ph * cw[2 * i];
      s1 += ph * cw[2 * i + 1];
    }
    qy[t] = fy - s0;
    qx[t] = fx - s1;
  }
  __syncthreads();

  const int wave = t >> 6, lane = t & 63;
#pragma unroll 4
  for (int p = 0; p < 28; ++p) {
    int xx = wave * 28 + p;
    float fy = qy[xx], fx = qx[xx];
    float y0f = fminf(fmaxf(floorf(fy), 0.f), 110.f);
    float x0f = fminf(fmaxf(floorf(fx), 0.f), 110.f);
    float ay = fminf(fmaxf(fy - y0f, 0.f), 1.f);
    float ax = fminf(fmaxf(fx - x0f, 0.f), 1.f);
    int y0 = (int)y0f, x0 = (int)x0f;
    const float* p00 = img + (((size_t)(b * 112 + y0) * 112 + x0) * 64) + lane;
    float v00 = p00[0], v01 = p00[64];
    float v10 = p00[112 * 64], v11 = p00[112 * 64 + 64];
    float top = v00 * (1.f - ax) + v01 * ax;
    float bot = v10 * (1.f - ax) + v11 * ax;
    tile[lane][xx] = top * (1.f - ay) + bot * ay;
  }
  __syncthreads();

  float* ob = out + (size_t)b * 64 * 12544 + y * 112;
  for (int i = 0; i < 28; ++i) {
    int idx = i * 256 + t;
    int cc = idx / 112, xx = idx - cc * 112;
    ob[(size_t)cc * 12544 + xx] = tile[cc][xx];
  }
}

extern "C" void kernel_launch(void* const* d_in, const int* in_sizes, int n_in,
                              void* d_out, int out_size, void* d_ws, size_t ws_size,
                              hipStream_t stream) {
  const float* x      = (const float*)d_in[0];
  const float* img    = (const float*)d_in[1];
  const float* scales = (const float*)d_in[2];
  const float* W1     = (const float*)d_in[3];
  const float* b1     = (const float*)d_in[4];
  const float* W2     = (const float*)d_in[5];
  const float* b2     = (const float*)d_in[6];
  const float* W3     = (const float*)d_in[7];
  const float* b3     = (const float*)d_in[8];
  const float* lmean  = (const float*)d_in[9];
  float* out = (float*)d_out;
  float* ws  = (float*)d_ws;

  float* P1   = ws;                       // 784*2048 floats
  float* P2   = P1 + (size_t)NB1 * 2048;  // 16*2048
  float* COEF = P2 + 16 * 2048;           // 16*80
  float* NORM = COEF + 16 * 80;           // 16

  k_gemm1<<<NB1, 256, 0, stream>>>(x, W1, P1);
  k_red  <<<128, 256, 0, stream>>>(P1, P2);
  k_small<<<16, 64, 0, stream>>>(P2, b1, W2, b2, W3, b3, lmean, scales,
                                 out + PRED_OFF, COEF, NORM);
  k_warp <<<16 * 112, 256, 0, stream>>>(img, COEF, NORM, out);
}